// Round 4
// baseline (529.268 us; speedup 1.0000x reference)
//
#include <hip/hip_runtime.h>
#include <cstdint>

typedef __attribute__((ext_vector_type(8))) short short8;
typedef __attribute__((ext_vector_type(4))) float f32x4;
typedef unsigned short u16;

__device__ __forceinline__ float b2f(u16 u) {
  union { unsigned int i; float f; } v; v.i = ((unsigned int)u) << 16; return v.f;
}
__device__ __forceinline__ u16 f2b(float f) {
  union { float f; unsigned int i; } v; v.f = f;
  unsigned int x = v.i;
  return (u16)((x + 0x7fffu + ((x >> 16) & 1u)) >> 16);
}
__device__ __forceinline__ float silu_f(float x) { return x / (1.0f + __expf(-x)); }

// dtype-flexible load: flag==1 -> float32 data, flag==0 -> bf16 data.
__device__ __forceinline__ float loadF(const void* p, long i, int isf32) {
  if (isf32) return ((const float*)p)[i];
  return b2f(((const u16*)p)[i]);
}

struct Ptrs { const void* p[20]; int n[20]; };

// f32 prepped-weight layout (float offsets)
#define FW_NW1 0
#define FW_NW2 4096
#define FW_UW1 8192
#define FW_UW2 12288
#define FW_EW1 16384
#define FW_NB1 16768
#define FW_NB2 16832
#define FW_UB1 16896
#define FW_UB2 16960
#define FW_EB1 17024
#define FW_EB2 17088
#define FW_MB1 17152
#define FW_MB2 17216
#define FW_TOTAL 17280

// bf16 transposed image layout (u16 offsets):
// [0,4608)      ew2T [64 n][72 k] (k<64 real)
// [4608,13312)  mw1T [64 n][136 k] (k<128 real)
// [13312,17920) mw2T [64 n][72 k]
#define IMG_EW2 0
#define IMG_MW1 4608
#define IMG_MW2 13312
#define IMG_TOTAL 17920

// ---------------------------------------------------------------------------
// Kernel 0: per-tensor dtype detection (f32 vs bf16), unchanged from R3.
// ---------------------------------------------------------------------------
__global__ __launch_bounds__(256) void detect_k(Ptrs a, int* flags) {
  int j = blockIdx.x;
  const u16* q = (const u16*)a.p[j];
  int n = a.n[j];
  int m = n < 4096 ? n : 4096;
  int cnt = 0;
  for (int i = threadIdx.x; i < m; i += 256) {
    unsigned e = (q[i] >> 7) & 0xffu;
    if (e >= 0xC0u) cnt++;
  }
  __shared__ int tot;
  if (threadIdx.x == 0) tot = 0;
  __syncthreads();
  if (cnt) atomicAdd(&tot, cnt);
  __syncthreads();
  if (threadIdx.x == 0) flags[j] = (tot >= 2) ? 1 : 0;
}

// ---------------------------------------------------------------------------
// Kernel 1: weight prep (unchanged from R3).
// ---------------------------------------------------------------------------
__global__ __launch_bounds__(256) void prep_k(Ptrs a, const int* flags,
                                              u16* img, float* fw) {
  int i = blockIdx.x * 256 + threadIdx.x;
  if (i < IMG_TOTAL) {
    u16 val = 0;
    if (i < IMG_MW1) {
      int nn = i / 72, k = i % 72;
      if (k < 64) val = f2b(loadF(a.p[10], (long)k * 64 + nn, flags[10]));
    } else if (i < IMG_MW2) {
      int t2 = i - IMG_MW1; int nn = t2 / 136, k = t2 % 136;
      if (k < 128) val = f2b(loadF(a.p[12], (long)k * 64 + nn, flags[12]));
    } else {
      int t2 = i - IMG_MW2; int nn = t2 / 72, k = t2 % 72;
      if (k < 64) val = f2b(loadF(a.p[14], (long)k * 64 + nn, flags[14]));
    }
    img[i] = val;
  } else if (i < IMG_TOTAL + FW_TOTAL) {
    int j = i - IMG_TOTAL;
    float v;
    if (j < 4096)            v = loadF(a.p[4],  j,          flags[4]);
    else if (j < 8192)       v = loadF(a.p[6],  j - 4096,   flags[6]);
    else if (j < 12288)      v = loadF(a.p[16], j - 8192,   flags[16]);
    else if (j < 16384)      v = loadF(a.p[18], j - 12288,  flags[18]);
    else if (j < 16768)      v = loadF(a.p[8],  j - 16384,  flags[8]);
    else {
      int b = j - 16768; int seg = b >> 6, c = b & 63;
      const void* bp; int bf;
      switch (seg) {
        case 0: bp = a.p[5];  bf = flags[5];  break;
        case 1: bp = a.p[7];  bf = flags[7];  break;
        case 2: bp = a.p[17]; bf = flags[17]; break;
        case 3: bp = a.p[19]; bf = flags[19]; break;
        case 4: bp = a.p[9];  bf = flags[9];  break;
        case 5: bp = a.p[11]; bf = flags[11]; break;
        case 6: bp = a.p[13]; bf = flags[13]; break;
        default: bp = a.p[15]; bf = flags[15]; break;
      }
      v = loadF(bp, c, bf);
    }
    fw[j] = v;
  }
}

// ---------------------------------------------------------------------------
// Sorting kernels: counting sort of edges by target.
// ---------------------------------------------------------------------------
__global__ __launch_bounds__(256) void hist_k(const int* __restrict__ eidx,
                                              int* __restrict__ cnt, long E, int G) {
  long i = (long)blockIdx.x * 256 + threadIdx.x;
  const long stride = (long)gridDim.x * 256;
  for (; i < E; i += stride) {
    int tg = eidx[E + i];
    if (tg >= 0 && tg < G) atomicAdd(&cnt[tg], 1);
  }
}

__global__ __launch_bounds__(1024) void scan_k(const int* __restrict__ cnt,
                                               int* __restrict__ cursor,
                                               int* __restrict__ evp, int G) {
  __shared__ int sd[1024];
  __shared__ int carry;
  const int t = threadIdx.x;
  if (t == 0) carry = 0;
  __syncthreads();
  for (int c0 = 0; c0 < G; c0 += 1024) {
    int i = c0 + t;
    int v = (i < G) ? cnt[i] : 0;
    sd[t] = v;
    __syncthreads();
    for (int off = 1; off < 1024; off <<= 1) {
      int x = (t >= off) ? sd[t - off] : 0;
      __syncthreads();
      sd[t] += x;
      __syncthreads();
    }
    int excl = sd[t] - v + carry;
    if (i < G) cursor[i] = excl;
    int tot = sd[1023];
    __syncthreads();
    if (t == 0) carry += tot;
    __syncthreads();
  }
  if (t == 0) *evp = carry;
}

// pack: src (17 bits, N<=131072) | tgt<<17 (15 bits, G<=32768)
__global__ __launch_bounds__(256) void scat_k(const int* __restrict__ eidx,
                                              int* __restrict__ cursor,
                                              unsigned int* __restrict__ pkS,
                                              long E, int G) {
  long i = (long)blockIdx.x * 256 + threadIdx.x;
  const long stride = (long)gridDim.x * 256;
  for (; i < E; i += stride) {
    int tg = eidx[E + i];
    if (tg >= 0 && tg < G) {
      int s = eidx[i];
      int p = atomicAdd(&cursor[tg], 1);
      pkS[p] = (unsigned int)s | ((unsigned int)tg << 17);
    }
  }
}

// ---------------------------------------------------------------------------
// Kernel 2: node MLP (unchanged from R3).
// ---------------------------------------------------------------------------
__global__ __launch_bounds__(256) void node_mlp(
    const void* x, const int* flags, const float* fw, u16* out, int nrows)
{
  __shared__ float xs[64][68];
  __shared__ float w1s[64][68];
  __shared__ float w2s[64][68];
  __shared__ float b1s[64];
  __shared__ float b2s[64];
  const int t = threadIdx.x;
  const int xf = flags[0];
  const long rbase = (long)blockIdx.x * 64;
  for (int i = t; i < 4096; i += 256) {
    int k = i >> 6, cc = i & 63;
    w1s[k][cc] = fw[FW_NW1 + i];
    w2s[k][cc] = fw[FW_NW2 + i];
  }
  if (t < 64) { b1s[t] = fw[FW_NB1 + t]; b2s[t] = fw[FW_NB2 + t]; }
  {
    int row = t >> 2, ch = t & 3;
    long rg = rbase + row;
    if (rg < nrows) {
      if (xf) {
        const float* xp = (const float*)x + rg * 64 + ch * 16;
#pragma unroll
        for (int m = 0; m < 16; ++m) xs[row][ch * 16 + m] = xp[m];
      } else {
        const u16* xp = (const u16*)x + rg * 64 + ch * 16;
#pragma unroll
        for (int m = 0; m < 16; ++m) xs[row][ch * 16 + m] = b2f(xp[m]);
      }
    } else {
#pragma unroll
      for (int m = 0; m < 16; ++m) xs[row][ch * 16 + m] = 0.f;
    }
  }
  __syncthreads();
  const int r0 = (t >> 4) * 4, c0 = (t & 15) * 4;
  float acc[4][4];
#pragma unroll
  for (int i = 0; i < 4; ++i)
#pragma unroll
    for (int j = 0; j < 4; ++j) acc[i][j] = b1s[c0 + j];
  for (int k = 0; k < 64; ++k) {
    float w0 = w1s[k][c0], w1v = w1s[k][c0 + 1], w2v = w1s[k][c0 + 2], w3v = w1s[k][c0 + 3];
#pragma unroll
    for (int i = 0; i < 4; ++i) {
      float a = xs[r0 + i][k];
      acc[i][0] = fmaf(a, w0, acc[i][0]);
      acc[i][1] = fmaf(a, w1v, acc[i][1]);
      acc[i][2] = fmaf(a, w2v, acc[i][2]);
      acc[i][3] = fmaf(a, w3v, acc[i][3]);
    }
  }
  __syncthreads();
#pragma unroll
  for (int i = 0; i < 4; ++i)
#pragma unroll
    for (int j = 0; j < 4; ++j) xs[r0 + i][c0 + j] = silu_f(acc[i][j]);
  __syncthreads();
  float acc2[4][4];
#pragma unroll
  for (int i = 0; i < 4; ++i)
#pragma unroll
    for (int j = 0; j < 4; ++j) acc2[i][j] = b2s[c0 + j];
  for (int k = 0; k < 64; ++k) {
    float w0 = w2s[k][c0], w1v = w2s[k][c0 + 1], w2v = w2s[k][c0 + 2], w3v = w2s[k][c0 + 3];
#pragma unroll
    for (int i = 0; i < 4; ++i) {
      float a = xs[r0 + i][k];
      acc2[i][0] = fmaf(a, w0, acc2[i][0]);
      acc2[i][1] = fmaf(a, w1v, acc2[i][1]);
      acc2[i][2] = fmaf(a, w2v, acc2[i][2]);
      acc2[i][3] = fmaf(a, w3v, acc2[i][3]);
    }
  }
#pragma unroll
  for (int i = 0; i < 4; ++i) {
    long rg = rbase + r0 + i;
    if (rg < nrows) {
#pragma unroll
      for (int j = 0; j < 4; ++j) out[rg * 64 + c0 + j] = f2b(acc2[i][j]);
    }
  }
}

// ---------------------------------------------------------------------------
// Kernel 3: edge pipeline over SORTED edges. 256 thr/block, ETILES x 64.
// Weights (B-fragments) read directly from global img (L1-resident).
// S4 writes messages (f32, +bias) to LDS; per-col run-reduction then writes
// each target once per 16-row chunk: interior runs plain stores, runs
// touching a chunk boundary atomicAdd.
// ---------------------------------------------------------------------------
#define ETILES 4

__global__ __launch_bounds__(256, 3) void edge_kernel(
    const void* node_pos, const void* grid_pos, const void* orient,
    const unsigned int* __restrict__ pkS, const int* __restrict__ evp,
    const u16* __restrict__ h_node, const u16* __restrict__ img,
    const float* __restrict__ fw, const int* __restrict__ flags,
    float* __restrict__ sums, int G)
{
  __shared__ __align__(16) u16 hA[64][136];    // msg_in: 0-63 h_node, 64-127 e_feat2
  __shared__ __align__(16) u16 ef1[64][72];    // hidden activations (bf16)
  __shared__ __align__(16) float msgf[64][66]; // per-tile messages f32 (+bias)
  __shared__ float eaf[64][6];                 // edge_attr f32
  __shared__ float w1e[6][64];                 // ew1 f32
  __shared__ float biasE[4][64];               // eb1, eb2, mb1, mb2
  __shared__ int src_s[64];
  __shared__ int tgt_s[64];

  const int t = threadIdx.x;
  const int pf = flags[1], gf = flags[2], of = flags[3];
  const int Ev = *evp;

  for (int i = t; i < 384; i += 256) w1e[i / 64][i % 64] = fw[FW_EW1 + i];
  { int seg = t >> 6, cc = t & 63; biasE[seg][cc] = fw[FW_EB1 + seg * 64 + cc]; }

  const int lane = t & 63, w = t >> 6;
  const int q = lane >> 4, c = lane & 15;
  const int m0 = w * 16;
  const u16* wE2 = img + IMG_EW2;
  const u16* wM1 = img + IMG_MW1;
  const u16* wM2 = img + IMG_MW2;
  const f32x4 z = {0.f, 0.f, 0.f, 0.f};

  for (int tile = 0; tile < ETILES; ++tile) {
    long base = ((long)blockIdx.x * ETILES + tile) * 64;
    if (base >= Ev) break;
    __syncthreads();  // guard LDS reuse from previous tile
    if (t < 64) {
      long eg = base + t;
      int s, tg;
      if (eg < Ev) {
        unsigned int pk = pkS[eg];
        s = (int)(pk & 0x1FFFFu);
        tg = (int)(pk >> 17);
      } else { s = 0; tg = -1; }
      src_s[t] = s;
      tgt_s[t] = tg;
      int tgc = (tg >= 0) ? tg : 0;
      float ps[3], rel[3], tr[3];
#pragma unroll
      for (int i = 0; i < 3; ++i) {
        ps[i] = loadF(node_pos, (long)s * 3 + i, pf);
        rel[i] = loadF(grid_pos, (long)tgc * 3 + i, gf) - ps[i];
      }
#pragma unroll
      for (int j = 0; j < 3; ++j) tr[j] = 0.f;
#pragma unroll
      for (int i = 0; i < 3; ++i)
#pragma unroll
        for (int j = 0; j < 3; ++j)
          tr[j] = fmaf(rel[i], loadF(orient, (long)s * 9 + i * 3 + j, of), tr[j]);
      eaf[t][0] = ps[0]; eaf[t][1] = ps[1]; eaf[t][2] = ps[2];
      eaf[t][3] = tr[0]; eaf[t][4] = tr[1]; eaf[t][5] = tr[2];
    }
    __syncthreads();  // src_s ready
    {
      int e = t >> 2, ch = t & 3;
      const u16* hp = h_node + (long)src_s[e] * 64 + ch * 16;
      short8 v0 = *(const short8*)hp;
      short8 v1 = *(const short8*)(hp + 8);
      *(short8*)&hA[e][ch * 16] = v0;
      *(short8*)&hA[e][ch * 16 + 8] = v1;
    }
    __syncthreads();  // eaf + hA(h_node half) ready

    // S1: edge MLP layer1 (K=6) f32 VALU -> silu -> ef1 (bf16)
    {
      int e = t >> 2, c0 = (t & 3) * 16;
      float a0 = eaf[e][0], a1 = eaf[e][1], a2 = eaf[e][2];
      float a3 = eaf[e][3], a4 = eaf[e][4], a5 = eaf[e][5];
      __align__(16) u16 tmp[16];
#pragma unroll
      for (int j = 0; j < 16; ++j) {
        int cc = c0 + j;
        float acc = biasE[0][cc];
        acc = fmaf(a0, w1e[0][cc], acc);
        acc = fmaf(a1, w1e[1][cc], acc);
        acc = fmaf(a2, w1e[2][cc], acc);
        acc = fmaf(a3, w1e[3][cc], acc);
        acc = fmaf(a4, w1e[4][cc], acc);
        acc = fmaf(a5, w1e[5][cc], acc);
        tmp[j] = f2b(silu_f(acc));
      }
      *(short8*)&ef1[e][c0] = *(const short8*)tmp;
      *(short8*)&ef1[e][c0 + 8] = *(const short8*)(tmp + 8);
    }
    __syncthreads();
    // S2: edge MLP layer2 (K=64) -> hA cols 64..127
    {
      short8 a0 = *(const short8*)&ef1[m0 + c][q * 8];
      short8 a1 = *(const short8*)&ef1[m0 + c][32 + q * 8];
#pragma unroll
      for (int nt = 0; nt < 4; ++nt) {
        short8 b0 = *(const short8*)&wE2[(nt * 16 + c) * 72 + q * 8];
        short8 b1v = *(const short8*)&wE2[(nt * 16 + c) * 72 + 32 + q * 8];
        f32x4 acc = __builtin_amdgcn_mfma_f32_16x16x32_bf16(a0, b0, z, 0, 0, 0);
        acc = __builtin_amdgcn_mfma_f32_16x16x32_bf16(a1, b1v, acc, 0, 0, 0);
#pragma unroll
        for (int r = 0; r < 4; ++r) {
          int row = m0 + q * 4 + r, col = nt * 16 + c;
          hA[row][64 + col] = f2b(acc[r] + biasE[1][col]);
        }
      }
    }
    __syncthreads();
    // S3: msg MLP layer1 (K=128) -> silu -> ef1
    {
      short8 a0 = *(const short8*)&hA[m0 + c][q * 8];
      short8 a1 = *(const short8*)&hA[m0 + c][32 + q * 8];
      short8 a2 = *(const short8*)&hA[m0 + c][64 + q * 8];
      short8 a3 = *(const short8*)&hA[m0 + c][96 + q * 8];
#pragma unroll
      for (int nt = 0; nt < 4; ++nt) {
        const u16* wp = &wM1[(nt * 16 + c) * 136];
        f32x4 acc = __builtin_amdgcn_mfma_f32_16x16x32_bf16(a0, *(const short8*)(wp + q * 8), z, 0, 0, 0);
        acc = __builtin_amdgcn_mfma_f32_16x16x32_bf16(a1, *(const short8*)(wp + 32 + q * 8), acc, 0, 0, 0);
        acc = __builtin_amdgcn_mfma_f32_16x16x32_bf16(a2, *(const short8*)(wp + 64 + q * 8), acc, 0, 0, 0);
        acc = __builtin_amdgcn_mfma_f32_16x16x32_bf16(a3, *(const short8*)(wp + 96 + q * 8), acc, 0, 0, 0);
#pragma unroll
        for (int r = 0; r < 4; ++r) {
          int row = m0 + q * 4 + r, col = nt * 16 + c;
          ef1[row][col] = f2b(silu_f(acc[r] + biasE[2][col]));
        }
      }
    }
    __syncthreads();
    // S4: msg MLP layer2 (K=64) -> msgf (f32, +bias)
    {
      short8 a0 = *(const short8*)&ef1[m0 + c][q * 8];
      short8 a1 = *(const short8*)&ef1[m0 + c][32 + q * 8];
#pragma unroll
      for (int nt = 0; nt < 4; ++nt) {
        short8 b0 = *(const short8*)&wM2[(nt * 16 + c) * 72 + q * 8];
        short8 b1v = *(const short8*)&wM2[(nt * 16 + c) * 72 + 32 + q * 8];
        f32x4 acc = __builtin_amdgcn_mfma_f32_16x16x32_bf16(a0, b0, z, 0, 0, 0);
        acc = __builtin_amdgcn_mfma_f32_16x16x32_bf16(a1, b1v, acc, 0, 0, 0);
#pragma unroll
        for (int r = 0; r < 4; ++r) {
          int row = m0 + q * 4 + r, col = nt * 16 + c;
          msgf[row][col] = acc[r] + biasE[3][col];
        }
      }
    }
    __syncthreads();
    // Reduce: wave w walks rows [16w,16w+16), col = lane. Runs of equal
    // target (sorted!) are flushed once: boundary-touching -> atomic,
    // interior -> plain store (sole writer globally).
    {
      int col = lane;
      int r0 = w * 16;
      int cur = tgt_s[r0];
      float run = msgf[r0][col];
      bool lopen = (r0 == 0) ? true : (tgt_s[r0 - 1] == cur);
#pragma unroll
      for (int r2 = 1; r2 < 16; ++r2) {
        int r = r0 + r2;
        int tg = tgt_s[r];
        float v = msgf[r][col];
        if (tg == cur) {
          run += v;
        } else {
          if (cur >= 0) {
            if (lopen) unsafeAtomicAdd(&sums[(long)cur * 64 + col], run);
            else sums[(long)cur * 64 + col] = run;
          }
          cur = tg; run = v; lopen = false;
        }
      }
      bool ropen = (r0 + 16 >= 64) ? true : (tgt_s[r0 + 16] == cur);
      if (cur >= 0) {
        if (lopen || ropen) unsafeAtomicAdd(&sums[(long)cur * 64 + col], run);
        else sums[(long)cur * 64 + col] = run;
      }
    }
  }
}

// ---------------------------------------------------------------------------
// Kernel 4: scatter-mean (int counts) + update MLP (f32) -> f32 out [G,64]
// ---------------------------------------------------------------------------
__global__ __launch_bounds__(256) void upd_mlp(
    const float* __restrict__ sums, const int* __restrict__ cnt,
    const float* __restrict__ fw, float* __restrict__ out, int nrows)
{
  __shared__ float xs[64][68];
  __shared__ float w1s[64][68];
  __shared__ float w2s[64][68];
  __shared__ float b1s[64];
  __shared__ float b2s[64];
  const int t = threadIdx.x;
  const long rbase = (long)blockIdx.x * 64;
  for (int i = t; i < 4096; i += 256) {
    int k = i >> 6, cc = i & 63;
    w1s[k][cc] = fw[FW_UW1 + i];
    w2s[k][cc] = fw[FW_UW2 + i];
  }
  if (t < 64) { b1s[t] = fw[FW_UB1 + t]; b2s[t] = fw[FW_UB2 + t]; }
  {
    int row = t >> 2, ch = t & 3;
    long rg = rbase + row;
    if (rg < nrows) {
      float inv = 1.0f / fmaxf((float)cnt[rg], 1.0f);
      const float* p = sums + rg * 64 + ch * 16;
#pragma unroll
      for (int m = 0; m < 16; ++m) xs[row][ch * 16 + m] = p[m] * inv;
    } else {
#pragma unroll
      for (int m = 0; m < 16; ++m) xs[row][ch * 16 + m] = 0.f;
    }
  }
  __syncthreads();
  const int r0 = (t >> 4) * 4, c0 = (t & 15) * 4;
  float acc[4][4];
#pragma unroll
  for (int i = 0; i < 4; ++i)
#pragma unroll
    for (int j = 0; j < 4; ++j) acc[i][j] = b1s[c0 + j];
  for (int k = 0; k < 64; ++k) {
    float w0 = w1s[k][c0], w1v = w1s[k][c0 + 1], w2v = w1s[k][c0 + 2], w3v = w1s[k][c0 + 3];
#pragma unroll
    for (int i = 0; i < 4; ++i) {
      float a = xs[r0 + i][k];
      acc[i][0] = fmaf(a, w0, acc[i][0]);
      acc[i][1] = fmaf(a, w1v, acc[i][1]);
      acc[i][2] = fmaf(a, w2v, acc[i][2]);
      acc[i][3] = fmaf(a, w3v, acc[i][3]);
    }
  }
  __syncthreads();
#pragma unroll
  for (int i = 0; i < 4; ++i)
#pragma unroll
    for (int j = 0; j < 4; ++j) xs[r0 + i][c0 + j] = silu_f(acc[i][j]);
  __syncthreads();
  float acc2[4][4];
#pragma unroll
  for (int i = 0; i < 4; ++i)
#pragma unroll
    for (int j = 0; j < 4; ++j) acc2[i][j] = b2s[c0 + j];
  for (int k = 0; k < 64; ++k) {
    float w0 = w2s[k][c0], w1v = w2s[k][c0 + 1], w2v = w2s[k][c0 + 2], w3v = w2s[k][c0 + 3];
#pragma unroll
    for (int i = 0; i < 4; ++i) {
      float a = xs[r0 + i][k];
      acc2[i][0] = fmaf(a, w0, acc2[i][0]);
      acc2[i][1] = fmaf(a, w1v, acc2[i][1]);
      acc2[i][2] = fmaf(a, w2v, acc2[i][2]);
      acc2[i][3] = fmaf(a, w3v, acc2[i][3]);
    }
  }
#pragma unroll
  for (int i = 0; i < 4; ++i) {
    long rg = rbase + r0 + i;
    if (rg < nrows) {
#pragma unroll
      for (int j = 0; j < 4; ++j) out[rg * 64 + c0 + j] = acc2[i][j];
    }
  }
}

// ---------------------------------------------------------------------------
extern "C" void kernel_launch(void* const* d_in, const int* in_sizes, int n_in,
                              void* d_out, int out_size, void* d_ws, size_t ws_size,
                              hipStream_t stream) {
  const int N = in_sizes[1] / 3;
  const int G = in_sizes[2] / 3;
  const long E = (long)in_sizes[4] / 2;

  char* ws = (char*)d_ws;
  int* flags = (int*)ws;                       // 20 ints; evp at int 24
  int* evp = flags + 24;
  float* sums = (float*)(ws + 256);
  size_t off = 256 + (size_t)G * 256;
  int* cnt = (int*)(ws + off);     off += (size_t)G * 4;
  int* cursor = (int*)(ws + off);  off += (size_t)G * 4;
  unsigned int* pkS = (unsigned int*)(ws + off); off += (size_t)E * 4;
  u16* h_node = (u16*)(ws + off);  off += (size_t)N * 128;
  u16* img = (u16*)(ws + off);     off += (size_t)IMG_TOTAL * 2;
  float* fw = (float*)(ws + off);

  // zero flags + sums + cnt (ws poisoned 0xAA before every timed launch)
  hipMemsetAsync(ws, 0, 256 + (size_t)G * 256 + (size_t)G * 4, stream);

  Ptrs a;
  const int map[20] = {0,1,2,3, 5,6,7,8, 9,10,11,12, 13,14,15,16, 17,18,19,20};
  for (int i = 0; i < 20; ++i) { a.p[i] = d_in[map[i]]; a.n[i] = in_sizes[map[i]]; }

  detect_k<<<20, 256, 0, stream>>>(a, flags);
  prep_k<<<(IMG_TOTAL + FW_TOTAL + 255) / 256, 256, 0, stream>>>(a, flags, img, fw);
  hist_k<<<1024, 256, 0, stream>>>((const int*)d_in[4], cnt, E, G);
  scan_k<<<1, 1024, 0, stream>>>(cnt, cursor, evp, G);
  node_mlp<<<(N + 63) / 64, 256, 0, stream>>>(d_in[0], flags, fw, h_node, N);
  scat_k<<<1024, 256, 0, stream>>>((const int*)d_in[4], cursor, pkS, E, G);
  edge_kernel<<<(int)((E + ETILES * 64 - 1) / (ETILES * 64)), 256, 0, stream>>>(
      d_in[1], d_in[2], d_in[3], pkS, evp, h_node, img, fw, flags,
      sums, G);
  upd_mlp<<<(G + 63) / 64, 256, 0, stream>>>(sums, cnt, fw, (float*)d_out, G);
}

// Round 5
// 468.870 us; speedup vs baseline: 1.1288x; 1.1288x over previous
//
#include <hip/hip_runtime.h>
#include <cstdint>

typedef __attribute__((ext_vector_type(8))) short short8;
typedef __attribute__((ext_vector_type(4))) float f32x4;
typedef unsigned short u16;

__device__ __forceinline__ float b2f(u16 u) {
  union { unsigned int i; float f; } v; v.i = ((unsigned int)u) << 16; return v.f;
}
__device__ __forceinline__ u16 f2b(float f) {
  union { float f; unsigned int i; } v; v.f = f;
  unsigned int x = v.i;
  return (u16)((x + 0x7fffu + ((x >> 16) & 1u)) >> 16);
}
__device__ __forceinline__ float silu_f(float x) { return x / (1.0f + __expf(-x)); }

// dtype-flexible load: flag==1 -> float32 data, flag==0 -> bf16 data.
__device__ __forceinline__ float loadF(const void* p, long i, int isf32) {
  if (isf32) return ((const float*)p)[i];
  return b2f(((const u16*)p)[i]);
}

struct Ptrs { const void* p[20]; int n[20]; };

// f32 prepped-weight layout (float offsets)
#define FW_NW1 0
#define FW_NW2 4096
#define FW_UW1 8192
#define FW_UW2 12288
#define FW_EW1 16384
#define FW_NB1 16768
#define FW_NB2 16832
#define FW_UB1 16896
#define FW_UB2 16960
#define FW_EB1 17024
#define FW_EB2 17088
#define FW_MB1 17152
#define FW_MB2 17216
#define FW_TOTAL 17280

// bf16 transposed image layout (u16 offsets):
// [0,4608)      ew2T [64 n][72 k] (k<64 real)
// [4608,13312)  mw1T [64 n][136 k] (k<128 real)
// [13312,17920) mw2T [64 n][72 k]
#define IMG_EW2 0
#define IMG_MW1 4608
#define IMG_MW2 13312
#define IMG_TOTAL 17920

// ---------------------------------------------------------------------------
// Kernel 0: per-tensor dtype detection (f32 vs bf16).
// ---------------------------------------------------------------------------
__global__ __launch_bounds__(256) void detect_k(Ptrs a, int* flags) {
  int j = blockIdx.x;
  const u16* q = (const u16*)a.p[j];
  int n = a.n[j];
  int m = n < 4096 ? n : 4096;
  int cnt = 0;
  for (int i = threadIdx.x; i < m; i += 256) {
    unsigned e = (q[i] >> 7) & 0xffu;
    if (e >= 0xC0u) cnt++;
  }
  __shared__ int tot;
  if (threadIdx.x == 0) tot = 0;
  __syncthreads();
  if (cnt) atomicAdd(&tot, cnt);
  __syncthreads();
  if (threadIdx.x == 0) flags[j] = (tot >= 2) ? 1 : 0;
}

// ---------------------------------------------------------------------------
// Kernel 1: weight prep (unchanged).
// ---------------------------------------------------------------------------
__global__ __launch_bounds__(256) void prep_k(Ptrs a, const int* flags,
                                              u16* img, float* fw) {
  int i = blockIdx.x * 256 + threadIdx.x;
  if (i < IMG_TOTAL) {
    u16 val = 0;
    if (i < IMG_MW1) {
      int nn = i / 72, k = i % 72;
      if (k < 64) val = f2b(loadF(a.p[10], (long)k * 64 + nn, flags[10]));
    } else if (i < IMG_MW2) {
      int t2 = i - IMG_MW1; int nn = t2 / 136, k = t2 % 136;
      if (k < 128) val = f2b(loadF(a.p[12], (long)k * 64 + nn, flags[12]));
    } else {
      int t2 = i - IMG_MW2; int nn = t2 / 72, k = t2 % 72;
      if (k < 64) val = f2b(loadF(a.p[14], (long)k * 64 + nn, flags[14]));
    }
    img[i] = val;
  } else if (i < IMG_TOTAL + FW_TOTAL) {
    int j = i - IMG_TOTAL;
    float v;
    if (j < 4096)            v = loadF(a.p[4],  j,          flags[4]);
    else if (j < 8192)       v = loadF(a.p[6],  j - 4096,   flags[6]);
    else if (j < 12288)      v = loadF(a.p[16], j - 8192,   flags[16]);
    else if (j < 16384)      v = loadF(a.p[18], j - 12288,  flags[18]);
    else if (j < 16768)      v = loadF(a.p[8],  j - 16384,  flags[8]);
    else {
      int b = j - 16768; int seg = b >> 6, c = b & 63;
      const void* bp; int bf;
      switch (seg) {
        case 0: bp = a.p[5];  bf = flags[5];  break;
        case 1: bp = a.p[7];  bf = flags[7];  break;
        case 2: bp = a.p[17]; bf = flags[17]; break;
        case 3: bp = a.p[19]; bf = flags[19]; break;
        case 4: bp = a.p[9];  bf = flags[9];  break;
        case 5: bp = a.p[11]; bf = flags[11]; break;
        case 6: bp = a.p[13]; bf = flags[13]; break;
        default: bp = a.p[15]; bf = flags[15]; break;
      }
      v = loadF(bp, c, bf);
    }
    fw[j] = v;
  }
}

// ---------------------------------------------------------------------------
// Counting sort of edges by target — parallel scan version.
// ---------------------------------------------------------------------------
__global__ __launch_bounds__(256) void hist_k(const int* __restrict__ eidx,
                                              int* __restrict__ cnt, long E, int G) {
  long i = (long)blockIdx.x * 256 + threadIdx.x;
  const long stride = (long)gridDim.x * 256;
  for (; i < E; i += stride) {
    int tg = eidx[E + i];
    if (tg >= 0 && tg < G) atomicAdd(&cnt[tg], 1);
  }
}

// per-1024-chunk exclusive scan (32 blocks); writes local prefix + block sums
__global__ __launch_bounds__(1024) void scan1_k(const int* __restrict__ cnt,
                                                int* __restrict__ cursor,
                                                int* __restrict__ bsum, int G) {
  __shared__ int sd[1024];
  const int t = threadIdx.x;
  int i = blockIdx.x * 1024 + t;
  int v = (i < G) ? cnt[i] : 0;
  sd[t] = v;
  __syncthreads();
  for (int off = 1; off < 1024; off <<= 1) {
    int x = (t >= off) ? sd[t - off] : 0;
    __syncthreads();
    sd[t] += x;
    __syncthreads();
  }
  if (i < G) cursor[i] = sd[t] - v;   // local exclusive prefix
  if (t == 1023) bsum[blockIdx.x] = sd[t];
}

// tiny top-level scan of 32 block sums
__global__ void scan2_k(const int* __restrict__ bsum, int* __restrict__ boffs,
                        int* __restrict__ evp, int nb) {
  if (threadIdx.x == 0 && blockIdx.x == 0) {
    int acc = 0;
    for (int i = 0; i < nb; ++i) { boffs[i] = acc; acc += bsum[i]; }
    *evp = acc;
  }
}

// pack: src (17 bits, N<=131072) | tgt<<17 (15 bits, G<=32768)
__global__ __launch_bounds__(256) void scat_k(const int* __restrict__ eidx,
                                              int* __restrict__ cursor,
                                              const int* __restrict__ boffs,
                                              unsigned int* __restrict__ pkS,
                                              long E, int G) {
  long i = (long)blockIdx.x * 256 + threadIdx.x;
  const long stride = (long)gridDim.x * 256;
  for (; i < E; i += stride) {
    int tg = eidx[E + i];
    if (tg >= 0 && tg < G) {
      int s = eidx[i];
      int p = atomicAdd(&cursor[tg], 1) + boffs[tg >> 10];
      pkS[p] = (unsigned int)s | ((unsigned int)tg << 17);
    }
  }
}

// ---------------------------------------------------------------------------
// Kernel 2: node MLP (unchanged, f32 VALU).
// ---------------------------------------------------------------------------
__global__ __launch_bounds__(256) void node_mlp(
    const void* x, const int* flags, const float* fw, u16* out, int nrows)
{
  __shared__ float xs[64][68];
  __shared__ float w1s[64][68];
  __shared__ float w2s[64][68];
  __shared__ float b1s[64];
  __shared__ float b2s[64];
  const int t = threadIdx.x;
  const int xf = flags[0];
  const long rbase = (long)blockIdx.x * 64;
  for (int i = t; i < 4096; i += 256) {
    int k = i >> 6, cc = i & 63;
    w1s[k][cc] = fw[FW_NW1 + i];
    w2s[k][cc] = fw[FW_NW2 + i];
  }
  if (t < 64) { b1s[t] = fw[FW_NB1 + t]; b2s[t] = fw[FW_NB2 + t]; }
  {
    int row = t >> 2, ch = t & 3;
    long rg = rbase + row;
    if (rg < nrows) {
      if (xf) {
        const float* xp = (const float*)x + rg * 64 + ch * 16;
#pragma unroll
        for (int m = 0; m < 16; ++m) xs[row][ch * 16 + m] = xp[m];
      } else {
        const u16* xp = (const u16*)x + rg * 64 + ch * 16;
#pragma unroll
        for (int m = 0; m < 16; ++m) xs[row][ch * 16 + m] = b2f(xp[m]);
      }
    } else {
#pragma unroll
      for (int m = 0; m < 16; ++m) xs[row][ch * 16 + m] = 0.f;
    }
  }
  __syncthreads();
  const int r0 = (t >> 4) * 4, c0 = (t & 15) * 4;
  float acc[4][4];
#pragma unroll
  for (int i = 0; i < 4; ++i)
#pragma unroll
    for (int j = 0; j < 4; ++j) acc[i][j] = b1s[c0 + j];
  for (int k = 0; k < 64; ++k) {
    float w0 = w1s[k][c0], w1v = w1s[k][c0 + 1], w2v = w1s[k][c0 + 2], w3v = w1s[k][c0 + 3];
#pragma unroll
    for (int i = 0; i < 4; ++i) {
      float a = xs[r0 + i][k];
      acc[i][0] = fmaf(a, w0, acc[i][0]);
      acc[i][1] = fmaf(a, w1v, acc[i][1]);
      acc[i][2] = fmaf(a, w2v, acc[i][2]);
      acc[i][3] = fmaf(a, w3v, acc[i][3]);
    }
  }
  __syncthreads();
#pragma unroll
  for (int i = 0; i < 4; ++i)
#pragma unroll
    for (int j = 0; j < 4; ++j) xs[r0 + i][c0 + j] = silu_f(acc[i][j]);
  __syncthreads();
  float acc2[4][4];
#pragma unroll
  for (int i = 0; i < 4; ++i)
#pragma unroll
    for (int j = 0; j < 4; ++j) acc2[i][j] = b2s[c0 + j];
  for (int k = 0; k < 64; ++k) {
    float w0 = w2s[k][c0], w1v = w2s[k][c0 + 1], w2v = w2s[k][c0 + 2], w3v = w2s[k][c0 + 3];
#pragma unroll
    for (int i = 0; i < 4; ++i) {
      float a = xs[r0 + i][k];
      acc2[i][0] = fmaf(a, w0, acc2[i][0]);
      acc2[i][1] = fmaf(a, w1v, acc2[i][1]);
      acc2[i][2] = fmaf(a, w2v, acc2[i][2]);
      acc2[i][3] = fmaf(a, w3v, acc2[i][3]);
    }
  }
#pragma unroll
  for (int i = 0; i < 4; ++i) {
    long rg = rbase + r0 + i;
    if (rg < nrows) {
#pragma unroll
      for (int j = 0; j < 4; ++j) out[rg * 64 + c0 + j] = f2b(acc2[i][j]);
    }
  }
}

// ---------------------------------------------------------------------------
// Kernel 3: edge pipeline over SORTED edges.
// LDS shrunk to ~31 KB (msgf overlaid on hA, dead after S3) -> 5 blocks/CU.
// ---------------------------------------------------------------------------
#define ETILES 4

__global__ __launch_bounds__(256, 5) void edge_kernel(
    const void* node_pos, const void* grid_pos, const void* orient,
    const unsigned int* __restrict__ pkS, const int* __restrict__ evp,
    const u16* __restrict__ h_node, const u16* __restrict__ img,
    const float* __restrict__ fw, const int* __restrict__ flags,
    float* __restrict__ sums, int G)
{
  __shared__ __align__(16) u16 hA[64][136];    // msg_in; after S3 reused as msgf
  __shared__ __align__(16) u16 ef1[64][72];    // hidden activations (bf16)
  __shared__ float eaf[64][6];                 // edge_attr f32
  __shared__ float w1e[6][64];                 // ew1 f32
  __shared__ float biasE[4][64];               // eb1, eb2, mb1, mb2
  __shared__ int src_s[64];
  __shared__ int tgt_s[64];
  float (*msgf)[66] = (float (*)[66])&hA[0][0];   // 64*66*4 = 16896 <= 17408

  const int t = threadIdx.x;
  const int pf = flags[1], gf = flags[2], of = flags[3];
  const int Ev = *evp;

  for (int i = t; i < 384; i += 256) w1e[i / 64][i % 64] = fw[FW_EW1 + i];
  { int seg = t >> 6, cc = t & 63; biasE[seg][cc] = fw[FW_EB1 + seg * 64 + cc]; }

  const int lane = t & 63, w = t >> 6;
  const int q = lane >> 4, c = lane & 15;
  const int m0 = w * 16;
  const u16* wE2 = img + IMG_EW2;
  const u16* wM1 = img + IMG_MW1;
  const u16* wM2 = img + IMG_MW2;
  const f32x4 z = {0.f, 0.f, 0.f, 0.f};

  for (int tile = 0; tile < ETILES; ++tile) {
    long base = ((long)blockIdx.x * ETILES + tile) * 64;
    if (base >= Ev) break;
    __syncthreads();  // previous tile's reduce still reads msgf/tgt_s
    if (t < 64) {
      long eg = base + t;
      int s, tg;
      if (eg < Ev) {
        unsigned int pk = pkS[eg];
        s = (int)(pk & 0x1FFFFu);
        tg = (int)(pk >> 17);
      } else { s = 0; tg = -1; }
      src_s[t] = s;
      tgt_s[t] = tg;
      int tgc = (tg >= 0) ? tg : 0;
      float ps[3], rel[3], tr[3];
#pragma unroll
      for (int i = 0; i < 3; ++i) {
        ps[i] = loadF(node_pos, (long)s * 3 + i, pf);
        rel[i] = loadF(grid_pos, (long)tgc * 3 + i, gf) - ps[i];
      }
#pragma unroll
      for (int j = 0; j < 3; ++j) tr[j] = 0.f;
#pragma unroll
      for (int i = 0; i < 3; ++i)
#pragma unroll
        for (int j = 0; j < 3; ++j)
          tr[j] = fmaf(rel[i], loadF(orient, (long)s * 9 + i * 3 + j, of), tr[j]);
      eaf[t][0] = ps[0]; eaf[t][1] = ps[1]; eaf[t][2] = ps[2];
      eaf[t][3] = tr[0]; eaf[t][4] = tr[1]; eaf[t][5] = tr[2];
    }
    __syncthreads();  // src_s ready (and msgf fully consumed)
    {
      int e = t >> 2, ch = t & 3;
      const u16* hp = h_node + (long)src_s[e] * 64 + ch * 16;
      short8 v0 = *(const short8*)hp;
      short8 v1 = *(const short8*)(hp + 8);
      *(short8*)&hA[e][ch * 16] = v0;
      *(short8*)&hA[e][ch * 16 + 8] = v1;
    }
    __syncthreads();  // eaf + hA(h_node half) ready

    // S1: edge MLP layer1 (K=6) f32 VALU -> silu -> ef1 (bf16)
    {
      int e = t >> 2, c0 = (t & 3) * 16;
      float a0 = eaf[e][0], a1 = eaf[e][1], a2 = eaf[e][2];
      float a3 = eaf[e][3], a4 = eaf[e][4], a5 = eaf[e][5];
      __align__(16) u16 tmp[16];
#pragma unroll
      for (int j = 0; j < 16; ++j) {
        int cc = c0 + j;
        float acc = biasE[0][cc];
        acc = fmaf(a0, w1e[0][cc], acc);
        acc = fmaf(a1, w1e[1][cc], acc);
        acc = fmaf(a2, w1e[2][cc], acc);
        acc = fmaf(a3, w1e[3][cc], acc);
        acc = fmaf(a4, w1e[4][cc], acc);
        acc = fmaf(a5, w1e[5][cc], acc);
        tmp[j] = f2b(silu_f(acc));
      }
      *(short8*)&ef1[e][c0] = *(const short8*)tmp;
      *(short8*)&ef1[e][c0 + 8] = *(const short8*)(tmp + 8);
    }
    __syncthreads();
    // S2: edge MLP layer2 (K=64) -> hA cols 64..127
    {
      short8 a0 = *(const short8*)&ef1[m0 + c][q * 8];
      short8 a1 = *(const short8*)&ef1[m0 + c][32 + q * 8];
#pragma unroll
      for (int nt = 0; nt < 4; ++nt) {
        short8 b0 = *(const short8*)&wE2[(nt * 16 + c) * 72 + q * 8];
        short8 b1v = *(const short8*)&wE2[(nt * 16 + c) * 72 + 32 + q * 8];
        f32x4 acc = __builtin_amdgcn_mfma_f32_16x16x32_bf16(a0, b0, z, 0, 0, 0);
        acc = __builtin_amdgcn_mfma_f32_16x16x32_bf16(a1, b1v, acc, 0, 0, 0);
#pragma unroll
        for (int r = 0; r < 4; ++r) {
          int row = m0 + q * 4 + r, col = nt * 16 + c;
          hA[row][64 + col] = f2b(acc[r] + biasE[1][col]);
        }
      }
    }
    __syncthreads();
    // S3: msg MLP layer1 (K=128) -> silu -> ef1
    {
      short8 a0 = *(const short8*)&hA[m0 + c][q * 8];
      short8 a1 = *(const short8*)&hA[m0 + c][32 + q * 8];
      short8 a2 = *(const short8*)&hA[m0 + c][64 + q * 8];
      short8 a3 = *(const short8*)&hA[m0 + c][96 + q * 8];
#pragma unroll
      for (int nt = 0; nt < 4; ++nt) {
        const u16* wp = &wM1[(nt * 16 + c) * 136];
        f32x4 acc = __builtin_amdgcn_mfma_f32_16x16x32_bf16(a0, *(const short8*)(wp + q * 8), z, 0, 0, 0);
        acc = __builtin_amdgcn_mfma_f32_16x16x32_bf16(a1, *(const short8*)(wp + 32 + q * 8), acc, 0, 0, 0);
        acc = __builtin_amdgcn_mfma_f32_16x16x32_bf16(a2, *(const short8*)(wp + 64 + q * 8), acc, 0, 0, 0);
        acc = __builtin_amdgcn_mfma_f32_16x16x32_bf16(a3, *(const short8*)(wp + 96 + q * 8), acc, 0, 0, 0);
#pragma unroll
        for (int r = 0; r < 4; ++r) {
          int row = m0 + q * 4 + r, col = nt * 16 + c;
          ef1[row][col] = f2b(silu_f(acc[r] + biasE[2][col]));
        }
      }
    }
    __syncthreads();  // hA dead from here: msgf overlays it
    // S4: msg MLP layer2 (K=64) -> msgf (f32, +bias)
    {
      short8 a0 = *(const short8*)&ef1[m0 + c][q * 8];
      short8 a1 = *(const short8*)&ef1[m0 + c][32 + q * 8];
#pragma unroll
      for (int nt = 0; nt < 4; ++nt) {
        short8 b0 = *(const short8*)&wM2[(nt * 16 + c) * 72 + q * 8];
        short8 b1v = *(const short8*)&wM2[(nt * 16 + c) * 72 + 32 + q * 8];
        f32x4 acc = __builtin_amdgcn_mfma_f32_16x16x32_bf16(a0, b0, z, 0, 0, 0);
        acc = __builtin_amdgcn_mfma_f32_16x16x32_bf16(a1, b1v, acc, 0, 0, 0);
#pragma unroll
        for (int r = 0; r < 4; ++r) {
          int row = m0 + q * 4 + r, col = nt * 16 + c;
          msgf[row][col] = acc[r] + biasE[3][col];
        }
      }
    }
    __syncthreads();
    // Reduce: wave w walks rows [16w,16w+16), col = lane. Runs of equal
    // target flushed once: boundary-touching -> atomic, interior -> store.
    {
      int col = lane;
      int r0 = w * 16;
      int cur = tgt_s[r0];
      float run = msgf[r0][col];
      bool lopen = (r0 == 0) ? true : (tgt_s[r0 - 1] == cur);
#pragma unroll
      for (int r2 = 1; r2 < 16; ++r2) {
        int r = r0 + r2;
        int tg = tgt_s[r];
        float v = msgf[r][col];
        if (tg == cur) {
          run += v;
        } else {
          if (cur >= 0) {
            if (lopen) unsafeAtomicAdd(&sums[(long)cur * 64 + col], run);
            else sums[(long)cur * 64 + col] = run;
          }
          cur = tg; run = v; lopen = false;
        }
      }
      bool ropen = (r0 + 16 >= 64) ? true : (tgt_s[r0 + 16] == cur);
      if (cur >= 0) {
        if (lopen || ropen) unsafeAtomicAdd(&sums[(long)cur * 64 + col], run);
        else sums[(long)cur * 64 + col] = run;
      }
    }
  }
}

// ---------------------------------------------------------------------------
// Kernel 4: scatter-mean (int counts) + update MLP (f32) -> f32 out [G,64]
// ---------------------------------------------------------------------------
__global__ __launch_bounds__(256) void upd_mlp(
    const float* __restrict__ sums, const int* __restrict__ cnt,
    const float* __restrict__ fw, float* __restrict__ out, int nrows)
{
  __shared__ float xs[64][68];
  __shared__ float w1s[64][68];
  __shared__ float w2s[64][68];
  __shared__ float b1s[64];
  __shared__ float b2s[64];
  const int t = threadIdx.x;
  const long rbase = (long)blockIdx.x * 64;
  for (int i = t; i < 4096; i += 256) {
    int k = i >> 6, cc = i & 63;
    w1s[k][cc] = fw[FW_UW1 + i];
    w2s[k][cc] = fw[FW_UW2 + i];
  }
  if (t < 64) { b1s[t] = fw[FW_UB1 + t]; b2s[t] = fw[FW_UB2 + t]; }
  {
    int row = t >> 2, ch = t & 3;
    long rg = rbase + row;
    if (rg < nrows) {
      float inv = 1.0f / fmaxf((float)cnt[rg], 1.0f);
      const float* p = sums + rg * 64 + ch * 16;
#pragma unroll
      for (int m = 0; m < 16; ++m) xs[row][ch * 16 + m] = p[m] * inv;
    } else {
#pragma unroll
      for (int m = 0; m < 16; ++m) xs[row][ch * 16 + m] = 0.f;
    }
  }
  __syncthreads();
  const int r0 = (t >> 4) * 4, c0 = (t & 15) * 4;
  float acc[4][4];
#pragma unroll
  for (int i = 0; i < 4; ++i)
#pragma unroll
    for (int j = 0; j < 4; ++j) acc[i][j] = b1s[c0 + j];
  for (int k = 0; k < 64; ++k) {
    float w0 = w1s[k][c0], w1v = w1s[k][c0 + 1], w2v = w1s[k][c0 + 2], w3v = w1s[k][c0 + 3];
#pragma unroll
    for (int i = 0; i < 4; ++i) {
      float a = xs[r0 + i][k];
      acc[i][0] = fmaf(a, w0, acc[i][0]);
      acc[i][1] = fmaf(a, w1v, acc[i][1]);
      acc[i][2] = fmaf(a, w2v, acc[i][2]);
      acc[i][3] = fmaf(a, w3v, acc[i][3]);
    }
  }
  __syncthreads();
#pragma unroll
  for (int i = 0; i < 4; ++i)
#pragma unroll
    for (int j = 0; j < 4; ++j) xs[r0 + i][c0 + j] = silu_f(acc[i][j]);
  __syncthreads();
  float acc2[4][4];
#pragma unroll
  for (int i = 0; i < 4; ++i)
#pragma unroll
    for (int j = 0; j < 4; ++j) acc2[i][j] = b2s[c0 + j];
  for (int k = 0; k < 64; ++k) {
    float w0 = w2s[k][c0], w1v = w2s[k][c0 + 1], w2v = w2s[k][c0 + 2], w3v = w2s[k][c0 + 3];
#pragma unroll
    for (int i = 0; i < 4; ++i) {
      float a = xs[r0 + i][k];
      acc2[i][0] = fmaf(a, w0, acc2[i][0]);
      acc2[i][1] = fmaf(a, w1v, acc2[i][1]);
      acc2[i][2] = fmaf(a, w2v, acc2[i][2]);
      acc2[i][3] = fmaf(a, w3v, acc2[i][3]);
    }
  }
#pragma unroll
  for (int i = 0; i < 4; ++i) {
    long rg = rbase + r0 + i;
    if (rg < nrows) {
#pragma unroll
      for (int j = 0; j < 4; ++j) out[rg * 64 + c0 + j] = acc2[i][j];
    }
  }
}

// ---------------------------------------------------------------------------
extern "C" void kernel_launch(void* const* d_in, const int* in_sizes, int n_in,
                              void* d_out, int out_size, void* d_ws, size_t ws_size,
                              hipStream_t stream) {
  const int N = in_sizes[1] / 3;
  const int G = in_sizes[2] / 3;
  const long E = (long)in_sizes[4] / 2;
  const int NB = (G + 1023) / 1024;   // scan blocks (32 for G=32768)

  char* ws = (char*)d_ws;
  int* flags = (int*)ws;                       // ints 0..19; evp at int 24
  int* evp = flags + 24;
  float* sums = (float*)(ws + 256);
  size_t off = 256 + (size_t)G * 256;
  int* cnt = (int*)(ws + off);     off += (size_t)G * 4;
  int* cursor = (int*)(ws + off);  off += (size_t)G * 4;
  int* bsum = (int*)(ws + off);    off += (size_t)NB * 4;
  int* boffs = (int*)(ws + off);   off += (size_t)NB * 4;
  off = (off + 255) & ~(size_t)255;
  unsigned int* pkS = (unsigned int*)(ws + off); off += (size_t)E * 4;
  u16* h_node = (u16*)(ws + off);  off += (size_t)N * 128;
  u16* img = (u16*)(ws + off);     off += (size_t)IMG_TOTAL * 2;
  float* fw = (float*)(ws + off);

  // zero flags + sums + cnt (cursor/bsum/boffs are fully overwritten)
  hipMemsetAsync(ws, 0, 256 + (size_t)G * 256 + (size_t)G * 4, stream);

  Ptrs a;
  const int map[20] = {0,1,2,3, 5,6,7,8, 9,10,11,12, 13,14,15,16, 17,18,19,20};
  for (int i = 0; i < 20; ++i) { a.p[i] = d_in[map[i]]; a.n[i] = in_sizes[map[i]]; }

  detect_k<<<20, 256, 0, stream>>>(a, flags);
  prep_k<<<(IMG_TOTAL + FW_TOTAL + 255) / 256, 256, 0, stream>>>(a, flags, img, fw);
  hist_k<<<1024, 256, 0, stream>>>((const int*)d_in[4], cnt, E, G);
  scan1_k<<<NB, 1024, 0, stream>>>(cnt, cursor, bsum, G);
  scan2_k<<<1, 64, 0, stream>>>(bsum, boffs, evp, NB);
  node_mlp<<<(N + 63) / 64, 256, 0, stream>>>(d_in[0], flags, fw, h_node, N);
  scat_k<<<1024, 256, 0, stream>>>((const int*)d_in[4], cursor, boffs, pkS, E, G);
  edge_kernel<<<(int)((E + ETILES * 64 - 1) / (ETILES * 64)), 256, 0, stream>>>(
      d_in[1], d_in[2], d_in[3], pkS, evp, h_node, img, fw, flags,
      sums, G);
  upd_mlp<<<(G + 63) / 64, 256, 0, stream>>>(sums, cnt, fw, (float*)d_out, G);
}